// Round 5
// baseline (999.651 us; speedup 1.0000x reference)
//
#include <hip/hip_runtime.h>
#include <hip/hip_bf16.h>

#define HF 64
#define EPS 1e-5f
#define SCAN_B 1024
#define BK 32            // nodes per bucket (dlocal = 5 bits; src fits 17 bits)

typedef __hip_bfloat16 bf16;

// ---- histogram of dst (in-degree, excluding self loop) ----
__global__ void k_hist(int* __restrict__ cnt, const int* __restrict__ dst, int E) {
    int e = blockIdx.x * blockDim.x + threadIdx.x;
    if (e < E) atomicAdd(&cnt[dst[e]], 1);
}

// ---- scan stage 1: per-1024-chunk exclusive scan + chunk totals; also dinv ----
__global__ void k_scan1(const int* __restrict__ cnt, int* __restrict__ chunk_scan,
                        int* __restrict__ bsum, float* __restrict__ dinv, int N) {
    __shared__ int tmp[2][SCAN_B];
    int t = threadIdx.x;
    int gid = blockIdx.x * SCAN_B + t;
    int v = (gid < N) ? cnt[gid] : 0;
    if (gid < N) dinv[gid] = rsqrtf((float)v + 1.0f);
    int pi = 0;
    tmp[0][t] = v;
    __syncthreads();
    for (int off = 1; off < SCAN_B; off <<= 1) {
        int val = tmp[pi][t];
        if (t >= off) val += tmp[pi][t - off];
        tmp[pi ^ 1][t] = val;
        pi ^= 1;
        __syncthreads();
    }
    int inc = tmp[pi][t];
    if (gid < N) chunk_scan[gid] = inc - v;
    if (t == SCAN_B - 1) bsum[blockIdx.x] = inc;
}

// ---- scan stage 2: exclusive scan of chunk totals; writes base[N] = E ----
__global__ void k_scan2(const int* __restrict__ bsum, int* __restrict__ bbase,
                        int* __restrict__ base, int NB, int N) {
    if (threadIdx.x == 0 && blockIdx.x == 0) {
        int acc = 0;
        for (int i = 0; i < NB; ++i) { bbase[i] = acc; acc += bsum[i]; }
        base[N] = acc;   // == E
    }
}

// ---- scan stage 3: base = chunk_scan + bbase ----
__global__ void k_scan3(const int* __restrict__ chunk_scan, const int* __restrict__ bbase,
                        int* __restrict__ base, int N) {
    int gid = blockIdx.x * SCAN_B + threadIdx.x;
    if (gid < N) base[gid] = chunk_scan[gid] + bbase[blockIdx.x];
}

// ---- bucket cursor init: bcur[beta] = base[beta*BK] ----
__global__ void k_binit(const int* __restrict__ base, int* __restrict__ bcur, int B, int N) {
    int b = blockIdx.x * blockDim.x + threadIdx.x;
    if (b < B) bcur[b] = base[b * BK];
}

// ---- pass B: append packed (dlocal<<17 | src) records to bucket frontiers ----
__global__ void k_passB(const int* __restrict__ src, const int* __restrict__ dst,
                        int* __restrict__ bcur, int* __restrict__ stage, int E) {
    int e = blockIdx.x * blockDim.x + threadIdx.x;
    if (e >= E) return;
    int d = dst[e];
    int beta = d >> 5;                 // d / BK
    int pos = atomicAdd(&bcur[beta], 1);
    stage[pos] = src[e] | ((d & (BK - 1)) << 17);
}

// ---- pass C: one block per bucket; scatter staged records into contiguous CSR rows ----
__global__ __launch_bounds__(256) void k_passC(const int* __restrict__ stage,
                                               const int* __restrict__ base,
                                               int* __restrict__ csr, int B, int N) {
    __shared__ int lcur[BK];
    int beta = blockIdx.x;
    int n0 = beta * BK;
    int n1 = n0 + BK; if (n1 > N) n1 = N;
    int nn = n1 - n0;
    int t = threadIdx.x;
    if (t < nn) lcur[t] = base[n0 + t];
    __syncthreads();
    int rbeg = base[n0], rend = base[n1];
    for (int i = rbeg + t; i < rend; i += 256) {
        int rec = stage[i];
        int s = rec & 0x1ffff;
        int dl = rec >> 17;
        int pos = atomicAdd(&lcur[dl], 1);
        csr[pos] = s;
    }
}

// ---- prescale: xs[n,c] = x[n,c] * dinv[n] ----
__global__ void k_prescale(const float* __restrict__ x, const float* __restrict__ dinv,
                           float* __restrict__ xs, int N5) {
    int i = blockIdx.x * blockDim.x + threadIdx.x;
    if (i < N5) xs[i] = x[i] * dinv[i / 5];
}

// ---- layer 1 fused: dinv[d]*(sum xs[s] + xs[d]) -> @W1 -> BN,ReLU -> hs1 (bf16, pre-scaled) ----
__global__ __launch_bounds__(256) void k_layer1(
    const float* __restrict__ xs, bf16* __restrict__ hout,
    const int* __restrict__ csr, const int* __restrict__ basep,
    const float* __restrict__ dinv,
    const float* __restrict__ W1, const float* __restrict__ b,
    const float* __restrict__ g, const float* __restrict__ be,
    const float* __restrict__ rm, const float* __restrict__ rv, int N) {
    __shared__ float sW[5 * HF];
    for (int i = threadIdx.x; i < 5 * HF; i += blockDim.x) sW[i] = W1[i];
    __syncthreads();

    int node = blockIdx.x * (blockDim.x >> 6) + (threadIdx.x >> 6);
    int lane = threadIdx.x & 63;
    if (node >= N) return;

    int j   = __builtin_amdgcn_readfirstlane(basep[node]);
    int end = __builtin_amdgcn_readfirstlane(basep[node + 1]);

    float acc = 0.f;
    if (lane < 5) acc = xs[node * 5 + lane];   // self term
#pragma unroll 4
    for (; j < end; ++j) {
        int s = csr[j];                        // wave-uniform -> scalar load
        if (lane < 5) acc += xs[s * 5 + lane];
    }
    float di = dinv[node];
    acc *= di;

    float out = b[lane];
#pragma unroll
    for (int k = 0; k < 5; ++k) out += __shfl(acc, k, 64) * sW[k * HF + lane];
    out = (out - rm[lane]) * (g[lane] * rsqrtf(rv[lane] + EPS)) + be[lane];
    out = fmaxf(out, 0.f);
    hout[node * HF + lane] = __float2bfloat16(out * di);   // pre-scale for next layer
}

// ---- layers 2/3 fused: dinv[d]*(sum hs[s] + hs[d]) -> @W -> BN,ReLU ----
template <int SCALE_OUT>
__global__ __launch_bounds__(256) void k_layer(
    const bf16* __restrict__ hs, void* __restrict__ hout_v,
    const int* __restrict__ csr, const int* __restrict__ basep,
    const float* __restrict__ dinv,
    const float* __restrict__ W, const float* __restrict__ b,
    const float* __restrict__ g, const float* __restrict__ be,
    const float* __restrict__ rm, const float* __restrict__ rv, int N) {
    __shared__ float sW[HF * HF];
    for (int i = threadIdx.x; i < HF * HF; i += blockDim.x) sW[i] = W[i];
    __syncthreads();

    int node = blockIdx.x * (blockDim.x >> 6) + (threadIdx.x >> 6);
    int lane = threadIdx.x & 63;
    if (node >= N) return;

    int j   = __builtin_amdgcn_readfirstlane(basep[node]);
    int end = __builtin_amdgcn_readfirstlane(basep[node + 1]);

    float acc = __bfloat162float(hs[node * HF + lane]);    // self term (already *dinv)
#pragma unroll 4
    for (; j < end; ++j) {
        int s = csr[j];                                    // wave-uniform -> scalar load
        acc += __bfloat162float(hs[s * HF + lane]);
    }
    float di = dinv[node];
    acc *= di;

    float out = b[lane];
#pragma unroll
    for (int k = 0; k < HF; ++k) out += __shfl(acc, k, 64) * sW[k * HF + lane];
    out = (out - rm[lane]) * (g[lane] * rsqrtf(rv[lane] + EPS)) + be[lane];
    out = fmaxf(out, 0.f);
    if (SCALE_OUT) {
        ((bf16*)hout_v)[node * HF + lane] = __float2bfloat16(out * di);
    } else {
        ((float*)hout_v)[node * HF + lane] = out;
    }
}

// ---- per-graph mean-pool + FC(64->32) relu + FC(32->2) sigmoid ----
__global__ void k_pool_fc(const float* __restrict__ h, const int* __restrict__ batch,
                          const float* __restrict__ Wf1, const float* __restrict__ bf1,
                          const float* __restrict__ Wf2, const float* __restrict__ bf2,
                          float* __restrict__ out, int N) {
    int g = blockIdx.x;
    int t = threadIdx.x;
    int f = t & 63, q = t >> 6;

    int lo = 0, hi = N;
    while (lo < hi) { int mid = (lo + hi) >> 1; if (batch[mid] < g) lo = mid + 1; else hi = mid; }
    int start = lo;
    hi = N;
    while (lo < hi) { int mid = (lo + hi) >> 1; if (batch[mid] < g + 1) lo = mid + 1; else hi = mid; }
    int end = lo;

    float sum = 0.f;
    for (int n = start + q; n < end; n += 4) sum += h[n * HF + f];

    __shared__ float red[4][HF];
    __shared__ float sp[HF];
    __shared__ float sh[32];
    red[q][f] = sum;
    __syncthreads();
    if (q == 0) {
        float s = red[0][f] + red[1][f] + red[2][f] + red[3][f];
        float cntf = (float)(end - start);
        sp[f] = s / fmaxf(cntf, 1.0f);
    }
    __syncthreads();
    if (t < 32) {
        float a = bf1[t];
#pragma unroll
        for (int k = 0; k < HF; ++k) a += sp[k] * Wf1[k * 32 + t];
        sh[t] = fmaxf(a, 0.f);
    }
    __syncthreads();
    if (t < 2) {
        float a = bf2[t];
#pragma unroll
        for (int k = 0; k < 32; ++k) a += sh[k] * Wf2[k * 2 + t];
        out[g * 2 + t] = 1.f / (1.f + expf(-a));
    }
}

extern "C" void kernel_launch(void* const* d_in, const int* in_sizes, int n_in,
                              void* d_out, int out_size, void* d_ws, size_t ws_size,
                              hipStream_t stream) {
    const float* x     = (const float*)d_in[0];
    const int*   ei    = (const int*)d_in[1];
    const int*   batch = (const int*)d_in[2];
    const float* W1 = (const float*)d_in[3];
    const float* b1 = (const float*)d_in[4];
    const float* g1 = (const float*)d_in[5];
    const float* be1 = (const float*)d_in[6];
    const float* rm1 = (const float*)d_in[7];
    const float* rv1 = (const float*)d_in[8];
    const float* W2 = (const float*)d_in[9];
    const float* b2 = (const float*)d_in[10];
    const float* g2 = (const float*)d_in[11];
    const float* be2 = (const float*)d_in[12];
    const float* rm2 = (const float*)d_in[13];
    const float* rv2 = (const float*)d_in[14];
    const float* W3 = (const float*)d_in[15];
    const float* b3 = (const float*)d_in[16];
    const float* g3 = (const float*)d_in[17];
    const float* be3 = (const float*)d_in[18];
    const float* rm3 = (const float*)d_in[19];
    const float* rv3 = (const float*)d_in[20];
    const float* Wf1 = (const float*)d_in[21];
    const float* bf1 = (const float*)d_in[22];
    const float* Wf2 = (const float*)d_in[23];
    const float* bf2 = (const float*)d_in[24];
    float* out = (float*)d_out;

    const int N = in_sizes[2];          // 100000
    const int E = in_sizes[1] / 2;      // 3200000
    const int G = out_size / 2;         // 256
    const int B = (N + BK - 1) / BK;    // buckets

    char* ws = (char*)d_ws;
    size_t off = 0;
    auto alloc = [&](size_t bytes) {
        char* p = ws + off;
        off += (bytes + 255) & ~(size_t)255;
        return p;
    };
    float* H3       = (float*)alloc((size_t)N * HF * sizeof(float));   // fp32 layer-3 out
    bf16*  HS1      = (bf16*) alloc((size_t)N * HF * sizeof(bf16));
    bf16*  HS2      = (bf16*) alloc((size_t)N * HF * sizeof(bf16));
    float* xs       = (float*)alloc((size_t)N * 5 * sizeof(float));
    float* dinv     = (float*)alloc((size_t)N * sizeof(float));
    int*   cnt      = (int*)  alloc((size_t)N * sizeof(int));
    int*   chunk_sc = (int*)  alloc((size_t)N * sizeof(int));
    int*   base     = (int*)  alloc(((size_t)N + 1) * sizeof(int));
    int*   bcur     = (int*)  alloc((size_t)B * sizeof(int));
    int*   bsum     = (int*)  alloc(256 * sizeof(int));
    int*   bbase    = (int*)  alloc(256 * sizeof(int));
    int*   csr      = (int*)  alloc((size_t)E * sizeof(int));
    int*   stage    = (int*)H3;   // alias: stage consumed (passC) before H3 written (layer 3)

    const int* src = ei;
    const int* dst = ei + E;

    const int BT = 256;
    int gE  = (E + BT - 1) / BT;
    int NB  = (N + SCAN_B - 1) / SCAN_B;
    int gW  = (N + 3) / 4;
    int gP  = (N * 5 + BT - 1) / BT;
    int gB  = (B + BT - 1) / BT;

    // ---- CSR build: hist -> scan -> bucket partition (passB) -> local scatter (passC) ----
    hipMemsetAsync(cnt, 0, (size_t)N * sizeof(int), stream);
    k_hist<<<gE, BT, 0, stream>>>(cnt, dst, E);
    k_scan1<<<NB, SCAN_B, 0, stream>>>(cnt, chunk_sc, bsum, dinv, N);
    k_scan2<<<1, 64, 0, stream>>>(bsum, bbase, base, NB, N);
    k_scan3<<<NB, SCAN_B, 0, stream>>>(chunk_sc, bbase, base, N);
    k_binit<<<gB, BT, 0, stream>>>(base, bcur, B, N);
    k_passB<<<gE, BT, 0, stream>>>(src, dst, bcur, stage, E);
    k_passC<<<B, BT, 0, stream>>>(stage, base, csr, B, N);
    k_prescale<<<gP, BT, 0, stream>>>(x, dinv, xs, N * 5);

    // ---- fused layers (agg-first by linearity; norm folded into activations) ----
    k_layer1<<<gW, BT, 0, stream>>>(xs, HS1, csr, base, dinv,
                                    W1, b1, g1, be1, rm1, rv1, N);
    k_layer<1><<<gW, BT, 0, stream>>>(HS1, HS2, csr, base, dinv,
                                      W2, b2, g2, be2, rm2, rv2, N);
    k_layer<0><<<gW, BT, 0, stream>>>(HS2, H3, csr, base, dinv,
                                      W3, b3, g3, be3, rm3, rv3, N);

    // ---- pool + MLP head ----
    k_pool_fc<<<G, BT, 0, stream>>>(H3, batch, Wf1, bf1, Wf2, bf2, out, N);
}

// Round 6
// 772.575 us; speedup vs baseline: 1.2939x; 1.2939x over previous
//
#include <hip/hip_runtime.h>
#include <hip/hip_bf16.h>

#define HF 64
#define EPS 1e-5f
#define SCAN_B 1024

#define BSH 9                    // bucket shift: 512 nodes / bucket
#define BKN (1 << BSH)           // 512 nodes per bucket
#define NBUCK_MAX 256            // >= ceil(N / BKN)
#define PB_T 256                 // passB threads
#define PB_EPT 32                // edges per thread
#define PB_TILE (PB_T * PB_EPT)  // 8192 edges per block

typedef __hip_bfloat16 bf16;

// ---- histogram of dst (in-degree, excluding self loop) ----
__global__ void k_hist(int* __restrict__ cnt, const int* __restrict__ dst, int E) {
    int e = blockIdx.x * blockDim.x + threadIdx.x;
    if (e < E) atomicAdd(&cnt[dst[e]], 1);
}

// ---- scan stage 1: per-1024-chunk exclusive scan + chunk totals; also dinv ----
__global__ void k_scan1(const int* __restrict__ cnt, int* __restrict__ chunk_scan,
                        int* __restrict__ bsum, float* __restrict__ dinv, int N) {
    __shared__ int tmp[2][SCAN_B];
    int t = threadIdx.x;
    int gid = blockIdx.x * SCAN_B + t;
    int v = (gid < N) ? cnt[gid] : 0;
    if (gid < N) dinv[gid] = rsqrtf((float)v + 1.0f);
    int pi = 0;
    tmp[0][t] = v;
    __syncthreads();
    for (int off = 1; off < SCAN_B; off <<= 1) {
        int val = tmp[pi][t];
        if (t >= off) val += tmp[pi][t - off];
        tmp[pi ^ 1][t] = val;
        pi ^= 1;
        __syncthreads();
    }
    int inc = tmp[pi][t];
    if (gid < N) chunk_scan[gid] = inc - v;
    if (t == SCAN_B - 1) bsum[blockIdx.x] = inc;
}

// ---- scan stage 2: exclusive scan of chunk totals; writes base[N] = E ----
__global__ void k_scan2(const int* __restrict__ bsum, int* __restrict__ bbase,
                        int* __restrict__ base, int NB, int N) {
    if (threadIdx.x == 0 && blockIdx.x == 0) {
        int acc = 0;
        for (int i = 0; i < NB; ++i) { bbase[i] = acc; acc += bsum[i]; }
        base[N] = acc;   // == E
    }
}

// ---- scan stage 3: base = chunk_scan + bbase ----
__global__ void k_scan3(const int* __restrict__ chunk_scan, const int* __restrict__ bbase,
                        int* __restrict__ base, int N) {
    int gid = blockIdx.x * SCAN_B + threadIdx.x;
    if (gid < N) base[gid] = chunk_scan[gid] + bbase[blockIdx.x];
}

// ---- bucket cursor init: bcur[beta] = base[beta*BKN] ----
__global__ void k_binit(const int* __restrict__ base, int* __restrict__ bcur, int B) {
    int b = blockIdx.x * blockDim.x + threadIdx.x;
    if (b < B) bcur[b] = base[b * BKN];
}

// ---- pass B: block-tiled binning; reserve per-(block,bucket) RUNS, write block-private ----
__global__ __launch_bounds__(PB_T) void k_passB(
    const int* __restrict__ src, const int* __restrict__ dst,
    int* __restrict__ bcur, int* __restrict__ stage, int E, int B) {
    __shared__ int scnt[NBUCK_MAX];
    __shared__ int sgoff[NBUCK_MAX];
    int t = threadIdx.x;
    int tile0 = blockIdx.x * PB_TILE;

    for (int b = t; b < B; b += PB_T) scnt[b] = 0;
    __syncthreads();

    int rec[PB_EPT];
    int bkt[PB_EPT];
#pragma unroll
    for (int k = 0; k < PB_EPT; ++k) {
        int e = tile0 + k * PB_T + t;
        bkt[k] = -1;
        if (e < E) {
            int d = dst[e];
            int s = src[e];
            int b = d >> BSH;
            bkt[k] = b;
            rec[k] = s | ((d & (BKN - 1)) << 17);
            atomicAdd(&scnt[b], 1);
        }
    }
    __syncthreads();

    // one global atomic per (block,bucket): reserve a contiguous run
    for (int b = t; b < B; b += PB_T) {
        int c = scnt[b];
        sgoff[b] = c ? atomicAdd(&bcur[b], c) : 0;
        scnt[b] = 0;
    }
    __syncthreads();

    // write records into block-private runs (lines stay in this XCD's L2)
#pragma unroll
    for (int k = 0; k < PB_EPT; ++k) {
        if (bkt[k] >= 0) {
            int loc = atomicAdd(&scnt[bkt[k]], 1);
            stage[sgoff[bkt[k]] + loc] = rec[k];
        }
    }
}

// ---- pass C: one block per bucket; scatter staged slice into contiguous CSR rows ----
__global__ __launch_bounds__(512) void k_passC(const int* __restrict__ stage,
                                               const int* __restrict__ base,
                                               int* __restrict__ csr, int N) {
    __shared__ int lcur[BKN];
    int beta = blockIdx.x;
    int n0 = beta * BKN;
    int n1 = n0 + BKN; if (n1 > N) n1 = N;
    int t = threadIdx.x;
    if (t < n1 - n0) lcur[t] = base[n0 + t];
    __syncthreads();
    int rbeg = base[n0], rend = base[n1];
    for (int i = rbeg + t; i < rend; i += 512) {
        int r = stage[i];
        int s = r & 0x1ffff;
        int dl = r >> 17;
        int pos = atomicAdd(&lcur[dl], 1);
        csr[pos] = s;
    }
}

// ---- prescale: xs[n,c] = x[n,c] * dinv[n] ----
__global__ void k_prescale(const float* __restrict__ x, const float* __restrict__ dinv,
                           float* __restrict__ xs, int N5) {
    int i = blockIdx.x * blockDim.x + threadIdx.x;
    if (i < N5) xs[i] = x[i] * dinv[i / 5];
}

// ---- layer 1 fused: dinv[d]*(sum xs[s] + xs[d]) -> @W1 -> BN,ReLU -> hs1 (bf16, pre-scaled) ----
__global__ __launch_bounds__(256) void k_layer1(
    const float* __restrict__ xs, bf16* __restrict__ hout,
    const int* __restrict__ csr, const int* __restrict__ basep,
    const float* __restrict__ dinv,
    const float* __restrict__ W1, const float* __restrict__ b,
    const float* __restrict__ g, const float* __restrict__ be,
    const float* __restrict__ rm, const float* __restrict__ rv, int N) {
    __shared__ float sW[5 * HF];
    for (int i = threadIdx.x; i < 5 * HF; i += blockDim.x) sW[i] = W1[i];
    __syncthreads();

    int node = blockIdx.x * (blockDim.x >> 6) + (threadIdx.x >> 6);
    int lane = threadIdx.x & 63;
    if (node >= N) return;

    int j   = __builtin_amdgcn_readfirstlane(basep[node]);
    int end = __builtin_amdgcn_readfirstlane(basep[node + 1]);

    float acc = 0.f;
    if (lane < 5) acc = xs[node * 5 + lane];   // self term
#pragma unroll 4
    for (; j < end; ++j) {
        int s = csr[j];                        // wave-uniform -> scalar load
        if (lane < 5) acc += xs[s * 5 + lane];
    }
    float di = dinv[node];
    acc *= di;

    float out = b[lane];
#pragma unroll
    for (int k = 0; k < 5; ++k) out += __shfl(acc, k, 64) * sW[k * HF + lane];
    out = (out - rm[lane]) * (g[lane] * rsqrtf(rv[lane] + EPS)) + be[lane];
    out = fmaxf(out, 0.f);
    hout[node * HF + lane] = __float2bfloat16(out * di);   // pre-scale for next layer
}

// ---- layers 2/3 fused: dinv[d]*(sum hs[s] + hs[d]) -> @W -> BN,ReLU ----
template <int SCALE_OUT>
__global__ __launch_bounds__(256) void k_layer(
    const bf16* __restrict__ hs, void* __restrict__ hout_v,
    const int* __restrict__ csr, const int* __restrict__ basep,
    const float* __restrict__ dinv,
    const float* __restrict__ W, const float* __restrict__ b,
    const float* __restrict__ g, const float* __restrict__ be,
    const float* __restrict__ rm, const float* __restrict__ rv, int N) {
    __shared__ float sW[HF * HF];
    for (int i = threadIdx.x; i < HF * HF; i += blockDim.x) sW[i] = W[i];
    __syncthreads();

    int node = blockIdx.x * (blockDim.x >> 6) + (threadIdx.x >> 6);
    int lane = threadIdx.x & 63;
    if (node >= N) return;

    int j   = __builtin_amdgcn_readfirstlane(basep[node]);
    int end = __builtin_amdgcn_readfirstlane(basep[node + 1]);

    float acc = __bfloat162float(hs[node * HF + lane]);    // self term (already *dinv)
#pragma unroll 4
    for (; j < end; ++j) {
        int s = csr[j];                                    // wave-uniform -> scalar load
        acc += __bfloat162float(hs[s * HF + lane]);
    }
    float di = dinv[node];
    acc *= di;

    float out = b[lane];
#pragma unroll
    for (int k = 0; k < HF; ++k) out += __shfl(acc, k, 64) * sW[k * HF + lane];
    out = (out - rm[lane]) * (g[lane] * rsqrtf(rv[lane] + EPS)) + be[lane];
    out = fmaxf(out, 0.f);
    if (SCALE_OUT) {
        ((bf16*)hout_v)[node * HF + lane] = __float2bfloat16(out * di);
    } else {
        ((float*)hout_v)[node * HF + lane] = out;
    }
}

// ---- per-graph mean-pool + FC(64->32) relu + FC(32->2) sigmoid ----
__global__ void k_pool_fc(const float* __restrict__ h, const int* __restrict__ batch,
                          const float* __restrict__ Wf1, const float* __restrict__ bf1,
                          const float* __restrict__ Wf2, const float* __restrict__ bf2,
                          float* __restrict__ out, int N) {
    int g = blockIdx.x;
    int t = threadIdx.x;
    int f = t & 63, q = t >> 6;

    int lo = 0, hi = N;
    while (lo < hi) { int mid = (lo + hi) >> 1; if (batch[mid] < g) lo = mid + 1; else hi = mid; }
    int start = lo;
    hi = N;
    while (lo < hi) { int mid = (lo + hi) >> 1; if (batch[mid] < g + 1) lo = mid + 1; else hi = mid; }
    int end = lo;

    float sum = 0.f;
    for (int n = start + q; n < end; n += 4) sum += h[n * HF + f];

    __shared__ float red[4][HF];
    __shared__ float sp[HF];
    __shared__ float sh[32];
    red[q][f] = sum;
    __syncthreads();
    if (q == 0) {
        float s = red[0][f] + red[1][f] + red[2][f] + red[3][f];
        float cntf = (float)(end - start);
        sp[f] = s / fmaxf(cntf, 1.0f);
    }
    __syncthreads();
    if (t < 32) {
        float a = bf1[t];
#pragma unroll
        for (int k = 0; k < HF; ++k) a += sp[k] * Wf1[k * 32 + t];
        sh[t] = fmaxf(a, 0.f);
    }
    __syncthreads();
    if (t < 2) {
        float a = bf2[t];
#pragma unroll
        for (int k = 0; k < 32; ++k) a += sh[k] * Wf2[k * 2 + t];
        out[g * 2 + t] = 1.f / (1.f + expf(-a));
    }
}

extern "C" void kernel_launch(void* const* d_in, const int* in_sizes, int n_in,
                              void* d_out, int out_size, void* d_ws, size_t ws_size,
                              hipStream_t stream) {
    const float* x     = (const float*)d_in[0];
    const int*   ei    = (const int*)d_in[1];
    const int*   batch = (const int*)d_in[2];
    const float* W1 = (const float*)d_in[3];
    const float* b1 = (const float*)d_in[4];
    const float* g1 = (const float*)d_in[5];
    const float* be1 = (const float*)d_in[6];
    const float* rm1 = (const float*)d_in[7];
    const float* rv1 = (const float*)d_in[8];
    const float* W2 = (const float*)d_in[9];
    const float* b2 = (const float*)d_in[10];
    const float* g2 = (const float*)d_in[11];
    const float* be2 = (const float*)d_in[12];
    const float* rm2 = (const float*)d_in[13];
    const float* rv2 = (const float*)d_in[14];
    const float* W3 = (const float*)d_in[15];
    const float* b3 = (const float*)d_in[16];
    const float* g3 = (const float*)d_in[17];
    const float* be3 = (const float*)d_in[18];
    const float* rm3 = (const float*)d_in[19];
    const float* rv3 = (const float*)d_in[20];
    const float* Wf1 = (const float*)d_in[21];
    const float* bf1 = (const float*)d_in[22];
    const float* Wf2 = (const float*)d_in[23];
    const float* bf2 = (const float*)d_in[24];
    float* out = (float*)d_out;

    const int N = in_sizes[2];            // 100000
    const int E = in_sizes[1] / 2;        // 3200000
    const int G = out_size / 2;           // 256
    const int B = (N + BKN - 1) / BKN;    // buckets (196)

    char* ws = (char*)d_ws;
    size_t off = 0;
    auto alloc = [&](size_t bytes) {
        char* p = ws + off;
        off += (bytes + 255) & ~(size_t)255;
        return p;
    };
    float* H3       = (float*)alloc((size_t)N * HF * sizeof(float));   // fp32 layer-3 out
    bf16*  HS1      = (bf16*) alloc((size_t)N * HF * sizeof(bf16));
    bf16*  HS2      = (bf16*) alloc((size_t)N * HF * sizeof(bf16));
    float* xs       = (float*)alloc((size_t)N * 5 * sizeof(float));
    float* dinv     = (float*)alloc((size_t)N * sizeof(float));
    int*   cnt      = (int*)  alloc((size_t)N * sizeof(int));
    int*   chunk_sc = (int*)  alloc((size_t)N * sizeof(int));
    int*   base     = (int*)  alloc(((size_t)N + 1) * sizeof(int));
    int*   bcur     = (int*)  alloc((size_t)NBUCK_MAX * sizeof(int));
    int*   bsum     = (int*)  alloc(256 * sizeof(int));
    int*   bbase    = (int*)  alloc(256 * sizeof(int));
    int*   csr      = (int*)  alloc((size_t)E * sizeof(int));
    int*   stage    = (int*)H3;   // alias: stage consumed (passC) before H3 written (layer 3)

    const int* src = ei;
    const int* dst = ei + E;

    const int BT = 256;
    int gE  = (E + BT - 1) / BT;
    int NB  = (N + SCAN_B - 1) / SCAN_B;
    int gW  = (N + 3) / 4;
    int gP  = (N * 5 + BT - 1) / BT;
    int gPB = (E + PB_TILE - 1) / PB_TILE;

    // ---- CSR build: hist -> scan -> run-reserving bucket partition -> local scatter ----
    hipMemsetAsync(cnt, 0, (size_t)N * sizeof(int), stream);
    k_hist<<<gE, BT, 0, stream>>>(cnt, dst, E);
    k_scan1<<<NB, SCAN_B, 0, stream>>>(cnt, chunk_sc, bsum, dinv, N);
    k_scan2<<<1, 64, 0, stream>>>(bsum, bbase, base, NB, N);
    k_scan3<<<NB, SCAN_B, 0, stream>>>(chunk_sc, bbase, base, N);
    k_binit<<<1, 256, 0, stream>>>(base, bcur, B);
    k_passB<<<gPB, PB_T, 0, stream>>>(src, dst, bcur, stage, E, B);
    k_passC<<<B, 512, 0, stream>>>(stage, base, csr, N);
    k_prescale<<<gP, BT, 0, stream>>>(x, dinv, xs, N * 5);

    // ---- fused layers (agg-first by linearity; norm folded into activations) ----
    k_layer1<<<gW, BT, 0, stream>>>(xs, HS1, csr, base, dinv,
                                    W1, b1, g1, be1, rm1, rv1, N);
    k_layer<1><<<gW, BT, 0, stream>>>(HS1, HS2, csr, base, dinv,
                                      W2, b2, g2, be2, rm2, rv2, N);
    k_layer<0><<<gW, BT, 0, stream>>>(HS2, H3, csr, base, dinv,
                                      W3, b3, g3, be3, rm3, rv3, N);

    // ---- pool + MLP head ----
    k_pool_fc<<<G, BT, 0, stream>>>(H3, batch, Wf1, bf1, Wf2, bf2, out, N);
}